// Round 10
// baseline (40.503 us; speedup 1.0000x reference)
//
#include <hip/hip_runtime.h>
#include <math.h>

#define BATCH 16
#define NKER  16
#define KS    5
#define UNITS 10
#define HIN   28
#define PO    12
#define NPOOL 144
#define NC    25
#define NCELL 2304           // 16*144
#define XSZ   928            // 784 image + 144 zero pad (gated gathers land there)
#define TPAD  28
#define GK    4              // kernels per staging group
#define NGRP  4
#define GFLT  (GK*NPOOL*UNITS)   // 5760 floats = 23040 B per group

// Single dispatch, 16 blocks (one per batch element), 512 threads, ~39KB LDS.
// fc_w is consumed via 4 staged LDS groups; staging bursts use 256 threads
// and overlap the (110-thread) accumulate phase.
__global__ __launch_bounds__(512, 2) void vdp_one(
    const float* __restrict__ x,       // [B,1,28,28]
    const float* __restrict__ conv_w,  // [K,1,5,5]
    const float* __restrict__ conv_s,  // [K]
    const float* __restrict__ fc_w,    // [2304,10]
    const float* __restrict__ fc_s,    // [10]
    float* __restrict__ out)           // [B*10] p ++ [B*100] sigma_out
{
    const int b = blockIdx.x;
    const int t = threadIdx.x;

    __shared__ float xs[XSZ];                 // 3712 B
    __shared__ float cw[NKER*NC];             // 1600
    __shared__ float sp1[NKER];
    __shared__ float sp2[UNITS];
    __shared__ short idx_s[NCELL];            // 4608
    __shared__ float fcw_g[GFLT];             // 23040
    __shared__ float T_s[GK][UNITS][TPAD];    // 4480
    __shared__ float A_sum[UNITS*UNITS];      // 400
    __shared__ float mu4_sum[UNITS];          // 40
    __shared__ float red_s[8][2];
    __shared__ float fin2[2];                 // [tr(sp1-weighted), mnorm]
    __shared__ float s4[100], tmp[100];
    __shared__ float p_s[10], r_s[10], q_s[10];

    // ---- staging (group 0 of fc_w included) ----
    {
        const float4* x4 = reinterpret_cast<const float4*>(x + b*HIN*HIN);
        if (t < 196) reinterpret_cast<float4*>(xs)[t] = x4[t];
        if (t >= 196 && t < 196 + (XSZ - 784)) xs[784 + t - 196] = 0.f;
        for (int i = t; i < NKER*NC; i += 512) cw[i] = conv_w[i];
        if (t < NKER) sp1[t] = log1pf(expf(conv_s[t]));
        if (t >= 32 && t < 32 + UNITS) sp2[t-32] = log1pf(expf(fc_s[t-32]));
        if (t >= 64 && t < 164) A_sum[t-64] = 0.f;
        if (t >= 192 && t < 192 + UNITS) mu4_sum[t-192] = 0.f;
        const float4* f4 = reinterpret_cast<const float4*>(fc_w);
        float4* d4 = reinterpret_cast<float4*>(fcw_g);
        for (int i = t; i < GFLT/4; i += 512) d4[i] = f4[i];
    }
    __syncthreads();

    // ---- phase 1: conv + relu + argmax-pool (no fc_w). wave w: k=2w,2w+1 ----
    float v_tr = 0.f, v_mn = 0.f;
    {
        const int wv = t >> 6;
        const int j  = t & 63;
        if (j < 48) {
            #pragma unroll
            for (int kk = 0; kk < 2; ++kk) {
                const int k = 2*wv + kk;
                const float sp1k = sp1[k];
                float cwr[NC];
                #pragma unroll
                for (int c = 0; c < NC; ++c) cwr[c] = cw[k*NC + c];
                #pragma unroll
                for (int ml = 0; ml < 3; ++ml) {
                    const int m  = j + 48*ml;
                    const int pi = m / PO, pj = m - pi*PO;
                    float w6[36];
                    #pragma unroll
                    for (int r = 0; r < 6; ++r)
                        #pragma unroll
                        for (int c2 = 0; c2 < 3; ++c2) {
                            const float2 v2 = *reinterpret_cast<const float2*>(
                                &xs[(2*pi + r)*HIN + 2*pj + 2*c2]);
                            w6[r*6 + 2*c2]     = v2.x;
                            w6[r*6 + 2*c2 + 1] = v2.y;
                        }
                    float a0 = 0.f, a1 = 0.f, a2 = 0.f, a3 = 0.f;
                    #pragma unroll
                    for (int kh = 0; kh < KS; ++kh)
                        #pragma unroll
                        for (int kw = 0; kw < KS; ++kw) {
                            const float w = cwr[kh*KS + kw];
                            a0 = fmaf(w, w6[kh*6 + kw],       a0);
                            a1 = fmaf(w, w6[kh*6 + kw + 1],   a1);
                            a2 = fmaf(w, w6[(kh+1)*6 + kw],   a2);
                            a3 = fmaf(w, w6[(kh+1)*6 + kw+1], a3);
                        }
                    const float r0 = fmaxf(a0, 0.f), r1 = fmaxf(a1, 0.f);
                    const float r2 = fmaxf(a2, 0.f), r3 = fmaxf(a3, 0.f);
                    float bestv = r0; int besta = 0;   // first-max wins (jnp.argmax)
                    if (r1 > bestv) { bestv = r1; besta = 1; }
                    if (r2 > bestv) { bestv = r2; besta = 2; }
                    if (r3 > bestv) { bestv = r3; besta = 3; }
                    const float mu3 = bestv;
                    const float g   = (mu3 > 0.f) ? 1.f : 0.f;

                    float ns = 0.f;                    // ||selected raw patch||^2
                    #pragma unroll
                    for (int kh = 0; kh < KS; ++kh)
                        #pragma unroll
                        for (int kw = 0; kw < KS; ++kw) {
                            const float v0 = w6[kh*6 + kw];
                            const float v1 = w6[kh*6 + kw + 1];
                            const float v2 = w6[(kh+1)*6 + kw];
                            const float v3 = w6[(kh+1)*6 + kw + 1];
                            const float val = (besta < 2) ? ((besta == 0) ? v0 : v1)
                                                          : ((besta == 2) ? v2 : v3);
                            ns = fmaf(val, val, ns);
                        }
                    const int oh = 2*pi + (besta >> 1);
                    const int ow = 2*pj + (besta & 1);
                    idx_s[k*NPOOL + m] = (short)((g > 0.f) ? (oh*HIN + ow) : 784);
                    v_tr = fmaf(g*sp1k, ns, v_tr);
                    v_mn = fmaf(mu3, mu3, v_mn);
                }
            }
        }
    }
    {
        float a0 = v_tr, a1 = v_mn;
        #pragma unroll
        for (int off = 32; off >= 1; off >>= 1) {
            a0 += __shfl_down(a0, off);
            a1 += __shfl_down(a1, off);
        }
        if ((t & 63) == 0) { red_s[t >> 6][0] = a0; red_s[t >> 6][1] = a1; }
    }
    __syncthreads();   // idx_s complete; red_s ready; fcw_g group 0 staged
    if (t < 2) {
        float a = 0.f;
        #pragma unroll
        for (int w = 0; w < 8; ++w) a += red_s[w][t];
        fin2[t] = a;
    }

    // ---- group loop ----
    for (int g = 0; g < NGRP; ++g) {
        // contraction: all 512 threads; 128 per kernel kl
        {
            const int kl = t >> 7;           // 0..3
            const int l  = t & 127;
            const int iq = l & 15;           // 16 i-chunks of 9
            const int ch = (l >> 4) & 3;     // 7 c's
            const int uh = l >> 6;           // 5 u's
            const int u0 = uh*5, c0 = ch*7;
            const int kg = g*GK + kl;
            int off_c[7];
            #pragma unroll
            for (int cc = 0; cc < 7; ++cc) {
                const int c = c0 + cc;
                off_c[cc] = (c/KS)*HIN + (c - (c/KS)*KS);
            }
            int idxr[9];
            const int ib = kg*NPOOL + iq*9;
            #pragma unroll
            for (int ii = 0; ii < 9; ++ii) idxr[ii] = idx_s[ib + ii];

            float acc[5][7];
            #pragma unroll
            for (int uu = 0; uu < 5; ++uu)
                #pragma unroll
                for (int cc = 0; cc < 7; ++cc) acc[uu][cc] = 0.f;

            const int rb = (kl*NPOOL + iq*9)*UNITS;
            #pragma unroll
            for (int ii = 0; ii < 9; ++ii) {
                float wv[5];
                #pragma unroll
                for (int uu = 0; uu < 5; ++uu) wv[uu] = fcw_g[rb + ii*UNITS + u0 + uu];
                float pv[7];
                #pragma unroll
                for (int cc = 0; cc < 7; ++cc) pv[cc] = xs[idxr[ii] + off_c[cc]];
                #pragma unroll
                for (int uu = 0; uu < 5; ++uu)
                    #pragma unroll
                    for (int cc = 0; cc < 7; ++cc)
                        acc[uu][cc] = fmaf(wv[uu], pv[cc], acc[uu][cc]);
            }
            #pragma unroll
            for (int off = 8; off >= 1; off >>= 1)
                #pragma unroll
                for (int uu = 0; uu < 5; ++uu)
                    #pragma unroll
                    for (int cc = 0; cc < 7; ++cc)
                        acc[uu][cc] += __shfl_down(acc[uu][cc], off, 16);
            if (iq == 0)
                #pragma unroll
                for (int uu = 0; uu < 5; ++uu)
                    #pragma unroll
                    for (int cc = 0; cc < 7; ++cc)
                        T_s[kl][u0+uu][c0+cc] = acc[uu][cc];
        }
        __syncthreads();

        // accumulate (t<110) overlapped with next-group staging (t>=256, 256 thr)
        if (t < 100) {
            const int u = t / UNITS, v = t - u*UNITS;
            float a = A_sum[t];
            #pragma unroll
            for (int kl = 0; kl < GK; ++kl) {
                float s = 0.f;
                #pragma unroll
                for (int c = 0; c < NC; ++c)
                    s = fmaf(T_s[kl][u][c], T_s[kl][v][c], s);
                a = fmaf(sp1[g*GK + kl], s, a);
            }
            A_sum[t] = a;
        } else if (t < 100 + UNITS) {
            const int u = t - 100;
            float a = mu4_sum[u];
            #pragma unroll
            for (int kl = 0; kl < GK; ++kl) {
                const int kg = g*GK + kl;
                float s = 0.f;
                #pragma unroll
                for (int c = 0; c < NC; ++c)
                    s = fmaf(cw[kg*NC + c], T_s[kl][u][c], s);
                a += s;
            }
            mu4_sum[u] = a;
        } else if (t >= 256 && g + 1 < NGRP) {
            const float4* f4 = reinterpret_cast<const float4*>(fc_w + (g+1)*GFLT);
            float4* d4 = reinterpret_cast<float4*>(fcw_g);
            for (int i = t - 256; i < GFLT/4; i += 256) d4[i] = f4[i];
        }
        __syncthreads();
    }

    // ---- finale ----
    if (t < 100) {
        const int u = t / UNITS, v = t - u*UNITS;
        float a = A_sum[t];
        if (u == v) a += sp2[u]*(fin2[0] + fin2[1]);
        s4[t] = a;
    }
    if (t == 511) {        // softmax(mu4) on an idle lane
        float mx = mu4_sum[0];
        #pragma unroll
        for (int u = 1; u < UNITS; ++u) mx = fmaxf(mx, mu4_sum[u]);
        float sum = 0.f;
        float e[UNITS];
        #pragma unroll
        for (int u = 0; u < UNITS; ++u) { e[u] = expf(mu4_sum[u] - mx); sum += e[u]; }
        #pragma unroll
        for (int u = 0; u < UNITS; ++u) p_s[u] = e[u] / sum;
    }
    __syncthreads();
    if (t < UNITS) {
        float r = 0.f;
        #pragma unroll
        for (int j = 0; j < UNITS; ++j) r = fmaf(p_s[j], s4[j*UNITS + t], r);
        r_s[t] = r;
    }
    __syncthreads();
    if (t < 100) {
        const int i = t / UNITS, k2 = t - i*UNITS;
        tmp[t] = p_s[i]*(s4[t] - r_s[k2]);
    }
    __syncthreads();
    if (t < UNITS) {
        float q = 0.f;
        #pragma unroll
        for (int kk = 0; kk < UNITS; ++kk) q = fmaf(tmp[t*UNITS + kk], p_s[kk], q);
        q_s[t] = q;
    }
    __syncthreads();
    if (t < 100) {
        const int i = t / UNITS, l = t - i*UNITS;
        out[BATCH*UNITS + b*UNITS*UNITS + t] = p_s[l]*(tmp[i*UNITS + l] - q_s[i]);
    }
    if (t < UNITS) out[b*UNITS + t] = p_s[t];
}

extern "C" void kernel_launch(void* const* d_in, const int* in_sizes, int n_in,
                              void* d_out, int out_size, void* d_ws, size_t ws_size,
                              hipStream_t stream) {
    const float* x      = (const float*)d_in[0];
    const float* conv_w = (const float*)d_in[1];
    const float* conv_s = (const float*)d_in[2];
    const float* fc_w   = (const float*)d_in[3];
    const float* fc_s   = (const float*)d_in[4];
    float* out = (float*)d_out;
    vdp_one<<<BATCH, 512, 0, stream>>>(x, conv_w, conv_s, fc_w, fc_s, out);
}